// Round 2
// baseline (1648.523 us; speedup 1.0000x reference)
//
#include <hip/hip_runtime.h>

#define HS 501
#define VS 533
#define KP 512
#define NB 2048
#define MAXN 32
#define NVT 10

typedef short s16x8 __attribute__((ext_vector_type(8)));
typedef float f32x4 __attribute__((ext_vector_type(4)));

// ---- static device buffers (rewritten every launch before being read) ----
__device__ ushort  g_Wb1[3*KP*KP];      // [gate][h][k] bf16, zero-padded
__device__ ushort  g_Wb2[2*KP*KP];      // [s][h][k]   (s=0:Wg, s=1:Wm)
__device__ ushort  g_Wf [128*KP];       // [j][k] rows 0..55=W1, 56..111=W2
__device__ float   g_giT[NVT*3*KP];     // [t][gate][h] = W_ih col t + b_ih
__device__ float   g_bhh[3*KP];
__device__ float   g_wgid[MAXN*KP];     // Wg[:,501+v]
__device__ float   g_wmid[MAXN*KP];     // Wm[:,501+v]
__device__ float   g_bgt[KP];
__device__ float   g_bias[128];
__device__ unsigned g_adjm[NB*MAXN];    // bit n = adj[b,n,v]
__device__ ushort  g_Hin[NB*KP];        // gathered GRU input H (bf16)
__device__ ushort  g_Hv [NB*KP];        // GRU output of current step (bf16)
__device__ ushort  g_gated[NB*MAXN*KP]; // cached gated rows (bf16)
__device__ int     g_adjfmt;            // 0=int32, 1=float32, 2=byte

__device__ __forceinline__ float b2f(ushort h){ return __uint_as_float(((unsigned)h)<<16); }
__device__ __forceinline__ ushort f2b(float f){
  unsigned u = __float_as_uint(f);
  u += 0x7FFFu + ((u>>16)&1u);
  return (ushort)(u>>16);
}
__device__ __forceinline__ float sigm(float x){ return 1.f/(1.f + __expf(-x)); }
__device__ __forceinline__ float tanh_f(float x){ return 1.f - 2.f/(1.f + __expf(2.f*x)); }

// ---------------- adj dtype detector ----------------
__global__ __launch_bounds__(256) void detect_adj(const void* __restrict__ adj){
  __shared__ int bad_i32, bad_f32;
  if (threadIdx.x == 0){ bad_i32 = 0; bad_f32 = 0; }
  __syncthreads();
  const int*   ai = (const int*)adj;
  const float* af = (const float*)adj;
  int li = 0, lf = 0;
  for (int i = threadIdx.x; i < 1024; i += 256){
    int w = ai[i];
    if (w != 0 && w != 1) li = 1;
    float f = af[i];
    if (f != 0.f && f != 1.f) lf = 1;
  }
  if (li) atomicOr(&bad_i32, 1);
  if (lf) atomicOr(&bad_f32, 1);
  __syncthreads();
  if (threadIdx.x == 0)
    g_adjfmt = (!bad_i32) ? 0 : (!bad_f32) ? 1 : 2;
}

// ---------------- setup kernels (run every launch) ----------------
__global__ __launch_bounds__(256) void prep_weights(const float* __restrict__ W_hh,
                                                    const float* __restrict__ Wg,
                                                    const float* __restrict__ Wm,
                                                    const float* __restrict__ W1,
                                                    const float* __restrict__ W2){
  int i = blockIdx.x*256 + threadIdx.x;
  const int NW1 = 3*KP*KP, NW2 = 2*KP*KP, NWF = 128*KP;
  if (i < NW1){
    int g = i >> 18; int rem = i & 0x3FFFF; int h = rem >> 9; int k = rem & 511;
    float v = (h < HS && k < HS) ? W_hh[(g*HS + h)*HS + k] : 0.f;
    g_Wb1[i] = f2b(v);
  } else if (i < NW1 + NW2){
    int j = i - NW1; int s = j >> 18; int rem = j & 0x3FFFF; int h = rem >> 9; int k = rem & 511;
    const float* src = s ? Wm : Wg;
    float v = (h < HS && k < HS) ? src[h*VS + k] : 0.f;
    g_Wb2[j] = f2b(v);
  } else if (i < NW1 + NW2 + NWF){
    int j = i - NW1 - NW2; int r = j >> 9; int k = j & 511;
    float v = 0.f;
    if (k < HS){
      if (r < 56) v = W1[r*HS + k];
      else if (r < 112) v = W2[(r-56)*HS + k];
    }
    g_Wf[j] = f2b(v);
  }
}

__global__ __launch_bounds__(256) void prep_tables(const float* __restrict__ W_ih,
                                                   const float* __restrict__ b_ih,
                                                   const float* __restrict__ b_hh,
                                                   const float* __restrict__ Wg,
                                                   const float* __restrict__ Wm,
                                                   const float* __restrict__ bg,
                                                   const float* __restrict__ b1,
                                                   const float* __restrict__ b2,
                                                   const void* __restrict__ adj){
  int i = blockIdx.x*256 + threadIdx.x;
  if (i < NVT*3*KP){
    int t = i / 1536; int rem = i - t*1536; int g = rem >> 9; int h = rem & 511;
    g_giT[i] = (h < HS) ? W_ih[(g*HS + h)*NVT + t] + b_ih[g*HS + h] : 0.f;
    return;
  }
  i -= NVT*3*KP;
  if (i < 3*KP){
    int g = i >> 9, h = i & 511;
    g_bhh[i] = (h < HS) ? b_hh[g*HS + h] : 0.f;
    return;
  }
  i -= 3*KP;
  if (i < MAXN*KP){
    int v = i >> 9, h = i & 511;
    g_wgid[i] = (h < HS) ? Wg[h*VS + HS + v] : 0.f;
    return;
  }
  i -= MAXN*KP;
  if (i < MAXN*KP){
    int v = i >> 9, h = i & 511;
    g_wmid[i] = (h < HS) ? Wm[h*VS + HS + v] : 0.f;
    return;
  }
  i -= MAXN*KP;
  if (i < KP){ g_bgt[i] = (i < HS) ? bg[i] : 0.f; return; }
  i -= KP;
  if (i < 128){ g_bias[i] = (i < 56) ? b1[i] : (i < 112) ? b2[i-56] : 0.f; return; }
  i -= 128;
  if (i < NB*MAXN){
    int b = i >> 5, v = i & 31;
    const int fmt = g_adjfmt;
    unsigned m = 0;
    const size_t base = (size_t)b*MAXN*MAXN + v;
    if (fmt == 0){
      const int* a = (const int*)adj;
      for (int n = 0; n < MAXN; ++n) if (a[base + (size_t)n*MAXN] != 0) m |= (1u << n);
    } else if (fmt == 1){
      const float* a = (const float*)adj;
      for (int n = 0; n < MAXN; ++n) if (a[base + (size_t)n*MAXN] != 0.f) m |= (1u << n);
    } else {
      const unsigned char* a = (const unsigned char*)adj;
      for (int n = 0; n < MAXN; ++n) if (a[base + (size_t)n*MAXN]) m |= (1u << n);
    }
    g_adjm[i] = m;
  }
}

// ---------------- step kernel A: gh = H @ W_hh^T (3 gates) + GRU ----------------
__global__ __launch_bounds__(256) void k_gru(int v, const int* __restrict__ node_types){
  const int tid = threadIdx.x;
  const int lane = tid & 63;
  const int w = tid >> 6;
  const int wm = w >> 1, wn = w & 1;
  const int m0 = blockIdx.y*64 + wm*32;
  const int h0 = blockIdx.x*64 + wn*32;
  const int lr = lane & 15;   // A-row / B-col / C-col within fragment
  const int lk = lane >> 4;   // k-block; C-rows = lk*4 + r

  f32x4 acc[2][2][3];
  #pragma unroll
  for (int a = 0; a < 2; ++a)
    #pragma unroll
    for (int c = 0; c < 2; ++c)
      #pragma unroll
      for (int g = 0; g < 3; ++g) acc[a][c][g] = (f32x4){0.f,0.f,0.f,0.f};

  if (v > 0){
    const ushort* Ap = g_Hin + (size_t)(m0 + lr)*KP + lk*8;
    const ushort* Bp = g_Wb1 + (size_t)(h0 + lr)*KP + lk*8;
    #pragma unroll
    for (int ks = 0; ks < 16; ++ks){
      s16x8 a0 = *(const s16x8*)(Ap + ks*32);
      s16x8 a1 = *(const s16x8*)(Ap + 16*KP + ks*32);
      #pragma unroll
      for (int g = 0; g < 3; ++g){
        s16x8 b0 = *(const s16x8*)(Bp + (size_t)g*KP*KP + ks*32);
        s16x8 b1 = *(const s16x8*)(Bp + (size_t)g*KP*KP + 16*KP + ks*32);
        acc[0][0][g] = __builtin_amdgcn_mfma_f32_16x16x32_bf16(a0, b0, acc[0][0][g], 0, 0, 0);
        acc[0][1][g] = __builtin_amdgcn_mfma_f32_16x16x32_bf16(a0, b1, acc[0][1][g], 0, 0, 0);
        acc[1][0][g] = __builtin_amdgcn_mfma_f32_16x16x32_bf16(a1, b0, acc[1][0][g], 0, 0, 0);
        acc[1][1][g] = __builtin_amdgcn_mfma_f32_16x16x32_bf16(a1, b1, acc[1][1][g], 0, 0, 0);
      }
    }
  }

  #pragma unroll
  for (int fm = 0; fm < 2; ++fm){
    #pragma unroll
    for (int r = 0; r < 4; ++r){
      const int b = m0 + fm*16 + lk*4 + r;
      const int t = node_types[b*MAXN + v];
      #pragma unroll
      for (int fh = 0; fh < 2; ++fh){
        const int h = h0 + fh*16 + lr;
        const float gir = g_giT[(t*3 + 0)*KP + h];
        const float giz = g_giT[(t*3 + 1)*KP + h];
        const float gin = g_giT[(t*3 + 2)*KP + h];
        const float ghr = acc[fm][fh][0][r] + g_bhh[0*KP + h];
        const float ghz = acc[fm][fh][1][r] + g_bhh[1*KP + h];
        const float ghn = acc[fm][fh][2][r] + g_bhh[2*KP + h];
        const float rr = sigm(gir + ghr);
        const float zz = sigm(giz + ghz);
        const float nn = tanh_f(gin + rr*ghn);
        const float hp = (v > 0) ? b2f(g_Hin[(size_t)b*KP + h]) : 0.f;
        const float hv = (1.f - zz)*nn + zz*hp;
        g_Hv[(size_t)b*KP + h] = (h < HS) ? f2b(hv) : (ushort)0;
      }
    }
  }
}

// ------- step kernel B: gated = sig(Hv@Wg^T+..)*(Hv@Wm^T+..) + gather next H -------
__global__ __launch_bounds__(256) void k_gated(int v){
  __shared__ float gv_s[64*64];
  const int tid = threadIdx.x;
  const int lane = tid & 63;
  const int w = tid >> 6;
  const int wm = w >> 1, wn = w & 1;
  const int m0 = blockIdx.y*64 + wm*32;
  const int h0 = blockIdx.x*64 + wn*32;
  const int lr = lane & 15;
  const int lk = lane >> 4;

  f32x4 acc[2][2][2];
  #pragma unroll
  for (int a = 0; a < 2; ++a)
    #pragma unroll
    for (int c = 0; c < 2; ++c)
      #pragma unroll
      for (int s = 0; s < 2; ++s) acc[a][c][s] = (f32x4){0.f,0.f,0.f,0.f};

  {
    const ushort* Ap = g_Hv  + (size_t)(m0 + lr)*KP + lk*8;
    const ushort* Bp = g_Wb2 + (size_t)(h0 + lr)*KP + lk*8;
    #pragma unroll
    for (int ks = 0; ks < 16; ++ks){
      s16x8 a0 = *(const s16x8*)(Ap + ks*32);
      s16x8 a1 = *(const s16x8*)(Ap + 16*KP + ks*32);
      #pragma unroll
      for (int s = 0; s < 2; ++s){
        s16x8 b0 = *(const s16x8*)(Bp + (size_t)s*KP*KP + ks*32);
        s16x8 b1 = *(const s16x8*)(Bp + (size_t)s*KP*KP + 16*KP + ks*32);
        acc[0][0][s] = __builtin_amdgcn_mfma_f32_16x16x32_bf16(a0, b0, acc[0][0][s], 0, 0, 0);
        acc[0][1][s] = __builtin_amdgcn_mfma_f32_16x16x32_bf16(a0, b1, acc[0][1][s], 0, 0, 0);
        acc[1][0][s] = __builtin_amdgcn_mfma_f32_16x16x32_bf16(a1, b0, acc[1][0][s], 0, 0, 0);
        acc[1][1][s] = __builtin_amdgcn_mfma_f32_16x16x32_bf16(a1, b1, acc[1][1][s], 0, 0, 0);
      }
    }
  }

  #pragma unroll
  for (int fm = 0; fm < 2; ++fm){
    #pragma unroll
    for (int r = 0; r < 4; ++r){
      const int b = m0 + fm*16 + lk*4 + r;
      #pragma unroll
      for (int fh = 0; fh < 2; ++fh){
        const int h = h0 + fh*16 + lr;
        const float sg = sigm(acc[fm][fh][0][r] + g_bgt[h] + g_wgid[v*KP + h]);
        const float mg = acc[fm][fh][1][r] + g_wmid[v*KP + h];
        float gv = sg * mg;
        if (h >= HS) gv = 0.f;
        g_gated[((size_t)b*MAXN + v)*KP + h] = f2b(gv);
        gv_s[(wm*32 + fm*16 + lk*4 + r)*64 + (wn*32 + fh*16 + lr)] = gv;
      }
    }
  }
  __syncthreads();

  if (v < MAXN - 1){
    for (int u = tid; u < 512; u += 256){
      const int bl = u >> 3, oct = u & 7;
      const int b = blockIdx.y*64 + bl;
      const int hb = blockIdx.x*64 + oct*8;
      unsigned m = g_adjm[b*MAXN + v + 1];
      float a8[8] = {0.f,0.f,0.f,0.f,0.f,0.f,0.f,0.f};
      while (m){
        const int n = __builtin_ctz(m); m &= m - 1;
        if (n == v){
          #pragma unroll
          for (int j = 0; j < 8; ++j) a8[j] += gv_s[bl*64 + oct*8 + j];
        } else {
          s16x8 gvv = *(const s16x8*)(g_gated + ((size_t)b*MAXN + n)*KP + hb);
          #pragma unroll
          for (int j = 0; j < 8; ++j) a8[j] += b2f((ushort)gvv[j]);
        }
      }
      s16x8 o;
      #pragma unroll
      for (int j = 0; j < 8; ++j) o[j] = (short)f2b(a8[j]);
      *(s16x8*)(g_Hin + (size_t)b*KP + hb) = o;
    }
  }
}

// ---------------- final: mu/logvar = Hg @ [W1;W2]^T + b ----------------
__global__ __launch_bounds__(256) void k_out(float* __restrict__ out){
  const int tid = threadIdx.x;
  const int lane = tid & 63;
  const int w = tid >> 6;
  const int wm = w >> 1, wn = w & 1;
  const int m0 = blockIdx.y*64 + wm*32;
  const int n0 = blockIdx.x*64 + wn*32;
  const int lr = lane & 15;
  const int lk = lane >> 4;

  f32x4 acc[2][2];
  #pragma unroll
  for (int a = 0; a < 2; ++a)
    #pragma unroll
    for (int c = 0; c < 2; ++c) acc[a][c] = (f32x4){0.f,0.f,0.f,0.f};

  const ushort* Ap = g_Hv + (size_t)(m0 + lr)*KP + lk*8;
  const ushort* Bp = g_Wf + (size_t)(n0 + lr)*KP + lk*8;
  #pragma unroll
  for (int ks = 0; ks < 16; ++ks){
    s16x8 a0 = *(const s16x8*)(Ap + ks*32);
    s16x8 a1 = *(const s16x8*)(Ap + 16*KP + ks*32);
    s16x8 b0 = *(const s16x8*)(Bp + ks*32);
    s16x8 b1 = *(const s16x8*)(Bp + 16*KP + ks*32);
    acc[0][0] = __builtin_amdgcn_mfma_f32_16x16x32_bf16(a0, b0, acc[0][0], 0, 0, 0);
    acc[0][1] = __builtin_amdgcn_mfma_f32_16x16x32_bf16(a0, b1, acc[0][1], 0, 0, 0);
    acc[1][0] = __builtin_amdgcn_mfma_f32_16x16x32_bf16(a1, b0, acc[1][0], 0, 0, 0);
    acc[1][1] = __builtin_amdgcn_mfma_f32_16x16x32_bf16(a1, b1, acc[1][1], 0, 0, 0);
  }

  #pragma unroll
  for (int fm = 0; fm < 2; ++fm){
    #pragma unroll
    for (int r = 0; r < 4; ++r){
      const int b = m0 + fm*16 + lk*4 + r;
      #pragma unroll
      for (int fn = 0; fn < 2; ++fn){
        const int j = n0 + fn*16 + lr;
        const float val = acc[fm][fn][r] + g_bias[j];
        if (j < 56)       out[(size_t)b*56 + j] = val;
        else if (j < 112) out[(size_t)NB*56 + (size_t)b*56 + (j - 56)] = val;
      }
    }
  }
}

extern "C" void kernel_launch(void* const* d_in, const int* in_sizes, int n_in,
                              void* d_out, int out_size, void* d_ws, size_t ws_size,
                              hipStream_t stream){
  const int*   node_types = (const int*)d_in[0];
  const void*  adj        = (const void*)d_in[1];
  const float* W_ih       = (const float*)d_in[2];
  const float* W_hh       = (const float*)d_in[3];
  const float* b_ih       = (const float*)d_in[4];
  const float* b_hh       = (const float*)d_in[5];
  const float* Wg         = (const float*)d_in[6];
  const float* bg         = (const float*)d_in[7];
  const float* Wm         = (const float*)d_in[8];
  const float* W1         = (const float*)d_in[9];
  const float* b1         = (const float*)d_in[10];
  const float* W2         = (const float*)d_in[11];
  const float* b2         = (const float*)d_in[12];
  float* out = (float*)d_out;

  const int NPREP1 = 3*KP*KP + 2*KP*KP + 128*KP;
  const int NPREP2 = NVT*3*KP + 3*KP + 2*MAXN*KP + KP + 128 + NB*MAXN;

  detect_adj  <<<1, 256, 0, stream>>>(adj);
  prep_weights<<<(NPREP1 + 255)/256, 256, 0, stream>>>(W_hh, Wg, Wm, W1, W2);
  prep_tables <<<(NPREP2 + 255)/256, 256, 0, stream>>>(W_ih, b_ih, b_hh, Wg, Wm, bg, b1, b2, adj);

  for (int v = 0; v < MAXN; ++v){
    k_gru<<<dim3(8, 32), 256, 0, stream>>>(v, node_types);
    if (v < MAXN - 1) k_gated<<<dim3(8, 32), 256, 0, stream>>>(v);
  }
  k_out<<<dim3(2, 32), 256, 0, stream>>>(out);
}